// Round 11
// baseline (496.541 us; speedup 1.0000x reference)
//
#include <hip/hip_runtime.h>
#include <hip/hip_bf16.h>

#define QQ 128
#define CC 256

typedef __attribute__((ext_vector_type(8))) _Float16 half8;
typedef __attribute__((ext_vector_type(4))) _Float16 half4;
typedef __attribute__((ext_vector_type(4))) float f32x4;

__device__ __forceinline__ unsigned short f2h_bits(float f) {
    union { _Float16 h; unsigned short u; } cv;
    cv.h = (_Float16)f;
    return cv.u;
}

__device__ __forceinline__ half8 cvt8(f32x4 a, f32x4 b) {
    half8 h;
    h[0] = (_Float16)a.x; h[1] = (_Float16)a.y; h[2] = (_Float16)a.z; h[3] = (_Float16)a.w;
    h[4] = (_Float16)b.x; h[5] = (_Float16)b.y; h[6] = (_Float16)b.z; h[7] = (_Float16)b.w;
    return h;
}

// sum of v over all 256 threads; red is float[4] shared scratch
__device__ __forceinline__ float block_sum256(float v, float* red, int tid) {
#pragma unroll
    for (int off = 32; off > 0; off >>= 1)
        v += __shfl_down(v, off, 64);
    if ((tid & 63) == 0) red[tid >> 6] = v;
    __syncthreads();
    float s = red[0] + red[1] + red[2] + red[3];
    __syncthreads();
    return s;
}

// ---------------- K1: MLP head (LN -> L1 relu -> L2 relu -> L3) ----------------
__global__ __launch_bounds__(256) void k_mlp_head(
    const float* __restrict__ cc, const float* __restrict__ ln0w, const float* __restrict__ ln0b,
    const float* __restrict__ W1, const float* __restrict__ b1,
    const float* __restrict__ W2, const float* __restrict__ b2,
    const float* __restrict__ W3, const float* __restrict__ b3,
    unsigned short* __restrict__ Mh)
{
    const int q = blockIdx.x, t = threadIdx.x;
    __shared__ float xs[CC], ys[CC];
    __shared__ float red[4];

    float v = cc[q * CC + t];
    float s = block_sum256(v, red, t);
    float m = s * (1.0f / CC);
    float d = v - m;
    float s2 = block_sum256(d * d, red, t);
    float rstd = rsqrtf(s2 * (1.0f / CC) + 1e-5f);
    xs[t] = d * rstd * ln0w[t] + ln0b[t];
    __syncthreads();

    float acc = 0.f;
    {
        const float* w = W1 + t * CC;
#pragma unroll 8
        for (int k = 0; k < CC; k += 4) {
            f32x4 wv = *(const f32x4*)(w + k);
            acc += xs[k] * wv.x + xs[k + 1] * wv.y + xs[k + 2] * wv.z + xs[k + 3] * wv.w;
        }
    }
    ys[t] = fmaxf(acc + b1[t], 0.f);
    __syncthreads();

    acc = 0.f;
    {
        const float* w = W2 + t * CC;
#pragma unroll 8
        for (int k = 0; k < CC; k += 4) {
            f32x4 wv = *(const f32x4*)(w + k);
            acc += ys[k] * wv.x + ys[k + 1] * wv.y + ys[k + 2] * wv.z + ys[k + 3] * wv.w;
        }
    }
    float x2 = fmaxf(acc + b2[t], 0.f);
    __syncthreads();
    xs[t] = x2;
    __syncthreads();

    acc = 0.f;
    {
        const float* w = W3 + t * CC;
#pragma unroll 8
        for (int k = 0; k < CC; k += 4) {
            f32x4 wv = *(const f32x4*)(w + k);
            acc += xs[k] * wv.x + xs[k + 1] * wv.y + xs[k + 2] * wv.z + xs[k + 3] * wv.w;
        }
    }
    Mh[q * CC + t] = f2h_bits(acc + b3[t]);
}

// ---------------- K2: fused logits + argmax + segment-sum (v2) ---------------
// Persistent: 256 blocks x 512 thr (8 waves), 1 block/CU, 256-VGPR budget.
// P read ONCE. Wave w owns clusters [16w,16w+16) (M frags in registers).
// Per 128-row chunk (double-buffered f16 LDS tile, XOR-swizzled):
//   issue next chunk loads -> MFMA (128 rows x own 16 clusters) -> argmax
//   (wave-local + cross-wave combine) -> logits store -> BALLOT-COMPACT rows
//   assigned to this wave (~16/chunk) into per-wave queue -> pipelined walk
//   accumulating into register bins -> ds_write next chunk.
__global__ __launch_bounds__(512, 1) void k_fused(
    const float* __restrict__ P, const unsigned short* __restrict__ Mh,
    float* __restrict__ out, float* __restrict__ partial, int N, int ntiles)
{
    __shared__ __align__(16) unsigned short Ps[2][128 * CC]; // 2 x 64 KB
    __shared__ float candv[8][128];
    __shared__ int   candi[8][128];
    __shared__ int   asg[128];
    __shared__ int   wq[8][128];                             // per-wave row queues

    const int tid = threadIdx.x;
    const int w = tid >> 6, l = tid & 63;
    const int lr = l & 15, lg = l >> 4;
    const int myc0 = w << 4;                  // first cluster this wave owns
    char* const PsB = reinterpret_cast<char*>(Ps);

    // M fragments: bfrag[kk] = Mh[16w+lr][kk*32 + lg*8 .. +8]
    half8 bfrag[8];
#pragma unroll
    for (int kk = 0; kk < 8; ++kk)
        bfrag[kk] = *reinterpret_cast<const half8*>(Mh + (myc0 + lr) * CC + kk * 32 + lg * 8);

    // register bins: named (static indexing only). lane owns channels 4l..4l+3.
    f32x4 b0={0,0,0,0},b1=b0,b2=b0,b3=b0,b4=b0,b5=b0,b6=b0,b7=b0;
    f32x4 b8=b0,b9=b0,b10=b0,b11=b0,b12=b0,b13=b0,b14=b0,b15=b0;

    // staging regs: 8 tasks x 2 f32x4. task id = tid + it*512:
    f32x4 sv[8][2];
    const int srow0 = tid >> 5;     // rows advance by 16 per it
    const int sck = tid & 31;

    const unsigned long long below = (1ull << l) - 1ull;

    // ---- prologue: stage chunk c0 into buf 0 ----
    int c = blockIdx.x;
    {
        const int p0 = c << 7;
#pragma unroll
        for (int it = 0; it < 8; ++it) {
            int row = srow0 + (it << 4);
            int pr = min(p0 + row, N - 1);
            const float* src = P + (size_t)pr * CC + (sck << 3);
            sv[it][0] = *reinterpret_cast<const f32x4*>(src);
            sv[it][1] = *reinterpret_cast<const f32x4*>(src + 4);
        }
#pragma unroll
        for (int it = 0; it < 8; ++it) {
            int row = srow0 + (it << 4);
            int boff = (row << 9) + (((sck << 4)) ^ ((row & 7) << 4));
            *reinterpret_cast<half8*>(PsB + boff) = cvt8(sv[it][0], sv[it][1]);
        }
    }
    __syncthreads();

    int cur = 0;
    for (; c < ntiles; ) {
        const int p0 = c << 7;
        const int cn = c + gridDim.x;
        const bool have_next = (cn < ntiles);

        // ---- issue next chunk's loads (hidden under compute) ----
        if (have_next) {
            const int np0 = cn << 7;
#pragma unroll
            for (int it = 0; it < 8; ++it) {
                int row = srow0 + (it << 4);
                int pr = min(np0 + row, N - 1);
                const float* src = P + (size_t)pr * CC + (sck << 3);
                sv[it][0] = *reinterpret_cast<const f32x4*>(src);
                sv[it][1] = *reinterpret_cast<const f32x4*>(src + 4);
            }
        }

        // ---- MFMA: rows 0..127 x clusters [16w,16w+16) ----
        const char* Pc = PsB + (cur << 16);
        const int swz = (lr & 7) << 4;
        f32x4 acc0={0,0,0,0},acc1=acc0,acc2=acc0,acc3=acc0,acc4=acc0,acc5=acc0,acc6=acc0,acc7=acc0;
#define MFMA_RS(accv, rs)                                                              \
        {                                                                              \
            const char* rowp = Pc + ((rs * 16 + lr) << 9);                             \
            _Pragma("unroll")                                                          \
            for (int kk = 0; kk < 8; ++kk) {                                           \
                half8 a = *reinterpret_cast<const half8*>(rowp + (((kk << 6) + (lg << 4)) ^ swz)); \
                accv = __builtin_amdgcn_mfma_f32_16x16x32_f16(a, bfrag[kk], accv, 0, 0, 0); \
            }                                                                          \
        }
        MFMA_RS(acc0, 0) MFMA_RS(acc1, 1) MFMA_RS(acc2, 2) MFMA_RS(acc3, 3)
        MFMA_RS(acc4, 4) MFMA_RS(acc5, 5) MFMA_RS(acc6, 6) MFMA_RS(acc7, 7)
#undef MFMA_RS

        // ---- per-wave argmax (over this wave's 16 clusters) ----
#define ARGMAX_RS(accv, rs)                                                            \
        {                                                                              \
            _Pragma("unroll")                                                          \
            for (int j = 0; j < 4; ++j) {                                              \
                float bv = accv[j]; int bi = myc0 + lr;                                \
                _Pragma("unroll")                                                      \
                for (int msk = 1; msk < 16; msk <<= 1) {                               \
                    float ov = __shfl_xor(bv, msk, 64);                                \
                    int oi = __shfl_xor(bi, msk, 64);                                  \
                    if (ov > bv || (ov == bv && oi < bi)) { bv = ov; bi = oi; }        \
                }                                                                      \
                if (lr == 0) {                                                         \
                    int r = rs * 16 + (lg << 2) + j;                                   \
                    candv[w][r] = bv; candi[w][r] = bi;                                \
                }                                                                      \
            }                                                                          \
        }
        ARGMAX_RS(acc0, 0) ARGMAX_RS(acc1, 1) ARGMAX_RS(acc2, 2) ARGMAX_RS(acc3, 3)
        ARGMAX_RS(acc4, 4) ARGMAX_RS(acc5, 5) ARGMAX_RS(acc6, 6) ARGMAX_RS(acc7, 7)
#undef ARGMAX_RS
        __syncthreads();

        // ---- logits store + cross-wave combine ----
#define STORE_RS(accv, rs)                                                             \
        {                                                                              \
            _Pragma("unroll")                                                          \
            for (int j = 0; j < 4; ++j) {                                              \
                int r = rs * 16 + (lg << 2) + j;                                       \
                int p = p0 + r;                                                        \
                if (p < N) out[((size_t)p << 7) + myc0 + lr] = accv[j];                \
            }                                                                          \
        }
        STORE_RS(acc0, 0) STORE_RS(acc1, 1) STORE_RS(acc2, 2) STORE_RS(acc3, 3)
        STORE_RS(acc4, 4) STORE_RS(acc5, 5) STORE_RS(acc6, 6) STORE_RS(acc7, 7)
#undef STORE_RS
        if (tid < 128) {
            float bv = candv[0][tid]; int bi = candi[0][tid];
#pragma unroll
            for (int wv = 1; wv < 8; ++wv) {
                float ov = candv[wv][tid];
                if (ov > bv) { bv = ov; bi = candi[wv][tid]; } // ascending cluster blocks: strict > keeps lowest
            }
            asg[tid] = bi;
        }
        __syncthreads();

        // ---- segsum: ballot-compact this wave's rows, then pipelined walk ----
        {
            const int rmax = min(128, N - p0);
            const int ra = asg[l], rb = asg[l + 64];
            const bool ma = ((unsigned)(ra - myc0) < 16u) && (l < rmax);
            const bool mb = ((unsigned)(rb - myc0) < 16u) && (l + 64 < rmax);
            const unsigned long long mka = __ballot(ma);
            const unsigned long long mkb = __ballot(mb);
            const int cnta = __popcll(mka);
            if (ma) wq[w][__popcll(mka & below)] = (l << 8) | (ra - myc0);
            if (mb) wq[w][cnta + __popcll(mkb & below)] = ((l + 64) << 8) | (rb - myc0);
            const int qn = cnta + __popcll(mkb);

#define ACC_ONE(E)                                                                     \
            {                                                                          \
                const int r_ = (E) >> 8;                                               \
                const int ar_ = __builtin_amdgcn_readfirstlane((E) & 255);             \
                const int cb_ = (l << 3) ^ ((r_ & 7) << 4);                            \
                half4 hv_ = *reinterpret_cast<const half4*>(Pc + (r_ << 9) + cb_);     \
                f32x4 fv_;                                                             \
                fv_.x = (float)hv_[0]; fv_.y = (float)hv_[1];                          \
                fv_.z = (float)hv_[2]; fv_.w = (float)hv_[3];                          \
                if (ar_ < 8) {                                                         \
                    if (ar_ < 4) { if (ar_ < 2) { if (ar_ == 0) b0 += fv_; else b1 += fv_; } \
                                   else         { if (ar_ == 2) b2 += fv_; else b3 += fv_; } } \
                    else         { if (ar_ < 6) { if (ar_ == 4) b4 += fv_; else b5 += fv_; } \
                                   else         { if (ar_ == 6) b6 += fv_; else b7 += fv_; } } \
                } else {                                                               \
                    if (ar_ < 12){ if (ar_ < 10){ if (ar_ == 8) b8 += fv_; else b9 += fv_; } \
                                   else         { if (ar_ == 10) b10 += fv_; else b11 += fv_; } } \
                    else         { if (ar_ < 14){ if (ar_ == 12) b12 += fv_; else b13 += fv_; } \
                                   else         { if (ar_ == 14) b14 += fv_; else b15 += fv_; } } \
                }                                                                      \
            }
            int i = 0;
            for (; i + 4 <= qn; i += 4) {
                const int e0 = wq[w][i], e1 = wq[w][i + 1], e2 = wq[w][i + 2], e3 = wq[w][i + 3];
                ACC_ONE(e0) ACC_ONE(e1) ACC_ONE(e2) ACC_ONE(e3)
            }
            for (; i < qn; ++i) {
                const int e = wq[w][i];
                ACC_ONE(e)
            }
#undef ACC_ONE
        }
        __syncthreads();

        // ---- write next chunk into the other buffer ----
        if (have_next) {
            char* Pn = PsB + ((cur ^ 1) << 16);
#pragma unroll
            for (int it = 0; it < 8; ++it) {
                int row = srow0 + (it << 4);
                int boff = (row << 9) + (((sck << 4)) ^ ((row & 7) << 4));
                *reinterpret_cast<half8*>(Pn + boff) = cvt8(sv[it][0], sv[it][1]);
            }
            __syncthreads();
        }
        c = cn; cur ^= 1;
    }

    // ---- flush bins to partial[bid] ----
    {
        float* pb = partial + (size_t)blockIdx.x * (QQ * CC) + (size_t)myc0 * CC + (l << 2);
        f32x4 bb[16] = {b0,b1,b2,b3,b4,b5,b6,b7,b8,b9,b10,b11,b12,b13,b14,b15};
#pragma unroll
        for (int i = 0; i < 16; ++i)
            *reinterpret_cast<f32x4*>(pb + (size_t)i * CC) = bb[i];
    }
}

// ---------------- K4: reduce partials + bottleneck LN -> Wb -> LN, + residual --
__global__ __launch_bounds__(256) void k_bottleneck(
    const float* __restrict__ partial, int nparts,
    const float* __restrict__ lnb1w, const float* __restrict__ lnb1b,
    const float* __restrict__ Wb,
    const float* __restrict__ lnb2w, const float* __restrict__ lnb2b,
    const float* __restrict__ cc, float* __restrict__ out2)
{
    const int q = blockIdx.x, t = threadIdx.x;
    __shared__ float xs[CC];
    __shared__ float red[4];

    float v = 0.f;
    {
        const float* src = partial + (size_t)q * CC + t;
        int part = 0;
        for (; part + 7 < nparts; part += 8) {
            float s0 = src[(size_t)(part + 0) * (QQ * CC)];
            float s1 = src[(size_t)(part + 1) * (QQ * CC)];
            float s2 = src[(size_t)(part + 2) * (QQ * CC)];
            float s3 = src[(size_t)(part + 3) * (QQ * CC)];
            float s4 = src[(size_t)(part + 4) * (QQ * CC)];
            float s5 = src[(size_t)(part + 5) * (QQ * CC)];
            float s6 = src[(size_t)(part + 6) * (QQ * CC)];
            float s7 = src[(size_t)(part + 7) * (QQ * CC)];
            v += ((s0 + s1) + (s2 + s3)) + ((s4 + s5) + (s6 + s7));
        }
        for (; part < nparts; ++part)
            v += src[(size_t)part * (QQ * CC)];
    }

    float s = block_sum256(v, red, t);
    float m = s * (1.0f / CC);
    float d = v - m;
    float s2 = block_sum256(d * d, red, t);
    float rstd = rsqrtf(s2 * (1.0f / CC) + 1e-5f);
    xs[t] = d * rstd * lnb1w[t] + lnb1b[t];
    __syncthreads();

    float acc = 0.f;
    {
        const float* wp = Wb + t * CC;
#pragma unroll 8
        for (int k = 0; k < CC; k += 4) {
            f32x4 wv = *(const f32x4*)(wp + k);
            acc += xs[k] * wv.x + xs[k + 1] * wv.y + xs[k + 2] * wv.z + xs[k + 3] * wv.w;
        }
    }
    float zs = block_sum256(acc, red, t);
    float zm = zs * (1.0f / CC);
    float zd = acc - zm;
    float zs2 = block_sum256(zd * zd, red, t);
    float zr = rsqrtf(zs2 * (1.0f / CC) + 1e-5f);
    out2[q * CC + t] = cc[q * CC + t] + zd * zr * lnb2w[t] + lnb2b[t];
}

extern "C" void kernel_launch(void* const* d_in, const int* in_sizes, int n_in,
                              void* d_out, int out_size, void* d_ws, size_t ws_size,
                              hipStream_t stream) {
    const float* cc   = (const float*)d_in[0];
    const float* P    = (const float*)d_in[1];
    const float* ln0w = (const float*)d_in[2];
    const float* ln0b = (const float*)d_in[3];
    const float* W1   = (const float*)d_in[4];
    const float* b1   = (const float*)d_in[5];
    const float* W2   = (const float*)d_in[6];
    const float* b2   = (const float*)d_in[7];
    const float* W3   = (const float*)d_in[8];
    const float* b3   = (const float*)d_in[9];
    const float* lnb1w = (const float*)d_in[10];
    const float* lnb1b = (const float*)d_in[11];
    const float* Wb   = (const float*)d_in[12];
    const float* lnb2w = (const float*)d_in[13];
    const float* lnb2b = (const float*)d_in[14];

    const int N = in_sizes[1] / CC;

    char* ws = (char*)d_ws;
    unsigned short* Mh = (unsigned short*)ws;               // 65536 B
    float* partial = (float*)(ws + 65536);                  // 256 * 128 KB = 32 MB

    float* logits = (float*)d_out;                          // [N][128]
    float* out2 = (float*)d_out + (size_t)N * QQ;           // [128][256]

    k_mlp_head<<<QQ, 256, 0, stream>>>(cc, ln0w, ln0b, W1, b1, W2, b2, W3, b3, Mh);

    const int ntiles = (N + 127) >> 7;
    const int nblk = 256;
    k_fused<<<nblk, 512, 0, stream>>>(P, Mh, logits, partial, N, ntiles);

    k_bottleneck<<<QQ, 256, 0, stream>>>(partial, nblk, lnb1w, lnb1b, Wb, lnb2w, lnb2b, cc, out2);
}

// Round 12
// 484.287 us; speedup vs baseline: 1.0253x; 1.0253x over previous
//
#include <hip/hip_runtime.h>
#include <hip/hip_bf16.h>

#define QQ 128
#define CC 256

typedef __attribute__((ext_vector_type(8))) _Float16 half8;
typedef __attribute__((ext_vector_type(4))) _Float16 half4;
typedef __attribute__((ext_vector_type(4))) float f32x4;

__device__ __forceinline__ unsigned short f2h_bits(float f) {
    union { _Float16 h; unsigned short u; } cv;
    cv.h = (_Float16)f;
    return cv.u;
}

__device__ __forceinline__ half8 cvt8(f32x4 a, f32x4 b) {
    half8 h;
    h[0] = (_Float16)a.x; h[1] = (_Float16)a.y; h[2] = (_Float16)a.z; h[3] = (_Float16)a.w;
    h[4] = (_Float16)b.x; h[5] = (_Float16)b.y; h[6] = (_Float16)b.z; h[7] = (_Float16)b.w;
    return h;
}

// sum of v over all 256 threads; red is float[4] shared scratch
__device__ __forceinline__ float block_sum256(float v, float* red, int tid) {
#pragma unroll
    for (int off = 32; off > 0; off >>= 1)
        v += __shfl_down(v, off, 64);
    if ((tid & 63) == 0) red[tid >> 6] = v;
    __syncthreads();
    float s = red[0] + red[1] + red[2] + red[3];
    __syncthreads();
    return s;
}

// ---------------- K1: MLP head (LN -> L1 relu -> L2 relu -> L3) ----------------
__global__ __launch_bounds__(256) void k_mlp_head(
    const float* __restrict__ cc, const float* __restrict__ ln0w, const float* __restrict__ ln0b,
    const float* __restrict__ W1, const float* __restrict__ b1,
    const float* __restrict__ W2, const float* __restrict__ b2,
    const float* __restrict__ W3, const float* __restrict__ b3,
    unsigned short* __restrict__ Mh)
{
    const int q = blockIdx.x, t = threadIdx.x;
    __shared__ float xs[CC], ys[CC];
    __shared__ float red[4];

    float v = cc[q * CC + t];
    float s = block_sum256(v, red, t);
    float m = s * (1.0f / CC);
    float d = v - m;
    float s2 = block_sum256(d * d, red, t);
    float rstd = rsqrtf(s2 * (1.0f / CC) + 1e-5f);
    xs[t] = d * rstd * ln0w[t] + ln0b[t];
    __syncthreads();

    float acc = 0.f;
    {
        const float* w = W1 + t * CC;
#pragma unroll 8
        for (int k = 0; k < CC; k += 4) {
            f32x4 wv = *(const f32x4*)(w + k);
            acc += xs[k] * wv.x + xs[k + 1] * wv.y + xs[k + 2] * wv.z + xs[k + 3] * wv.w;
        }
    }
    ys[t] = fmaxf(acc + b1[t], 0.f);
    __syncthreads();

    acc = 0.f;
    {
        const float* w = W2 + t * CC;
#pragma unroll 8
        for (int k = 0; k < CC; k += 4) {
            f32x4 wv = *(const f32x4*)(w + k);
            acc += ys[k] * wv.x + ys[k + 1] * wv.y + ys[k + 2] * wv.z + ys[k + 3] * wv.w;
        }
    }
    float x2 = fmaxf(acc + b2[t], 0.f);
    __syncthreads();
    xs[t] = x2;
    __syncthreads();

    acc = 0.f;
    {
        const float* w = W3 + t * CC;
#pragma unroll 8
        for (int k = 0; k < CC; k += 4) {
            f32x4 wv = *(const f32x4*)(w + k);
            acc += xs[k] * wv.x + xs[k + 1] * wv.y + xs[k + 2] * wv.z + xs[k + 3] * wv.w;
        }
    }
    Mh[q * CC + t] = f2h_bits(acc + b3[t]);
}

// ---------------- K2: fused logits + argmax + segment-sum (v3) ---------------
// v3 = v2 with SINGLE LDS P buffer (next chunk lives in registers, not LDS):
// 64 KB Ps + 12.5 KB aux = ~77 KB -> 2 blocks/CU, 16 waves/CU. Cross-block
// overlap hides the per-chunk phase chain (v2's failure was 1 block/CU).
__global__ __launch_bounds__(512, 2) void k_fused(
    const float* __restrict__ P, const unsigned short* __restrict__ Mh,
    float* __restrict__ out, float* __restrict__ partial, int N, int ntiles)
{
    __shared__ __align__(16) unsigned short Ps[128 * CC];    // 64 KB, swizzled
    __shared__ float candv[8][128];
    __shared__ int   candi[8][128];
    __shared__ int   asg[128];
    __shared__ int   wq[8][128];                             // per-wave row queues

    const int tid = threadIdx.x;
    const int w = tid >> 6, l = tid & 63;
    const int lr = l & 15, lg = l >> 4;
    const int myc0 = w << 4;                  // first cluster this wave owns
    char* const PsB = reinterpret_cast<char*>(Ps);

    // M fragments: bfrag[kk] = Mh[16w+lr][kk*32 + lg*8 .. +8]
    half8 bfrag[8];
#pragma unroll
    for (int kk = 0; kk < 8; ++kk)
        bfrag[kk] = *reinterpret_cast<const half8*>(Mh + (myc0 + lr) * CC + kk * 32 + lg * 8);

    // register bins: named (static indexing only). lane owns channels 4l..4l+3.
    f32x4 b0={0,0,0,0},b1=b0,b2=b0,b3=b0,b4=b0,b5=b0,b6=b0,b7=b0;
    f32x4 b8=b0,b9=b0,b10=b0,b11=b0,b12=b0,b13=b0,b14=b0,b15=b0;

    // staging regs: 8 tasks x 2 f32x4. task id = tid + it*512
    f32x4 sv[8][2];
    const int srow0 = tid >> 5;     // rows advance by 16 per it
    const int sck = tid & 31;

    const unsigned long long below = (1ull << l) - 1ull;

    // ---- prologue: stage chunk c0 ----
    int c = blockIdx.x;
    {
        const int p0 = c << 7;
#pragma unroll
        for (int it = 0; it < 8; ++it) {
            int row = srow0 + (it << 4);
            int pr = min(p0 + row, N - 1);
            const float* src = P + (size_t)pr * CC + (sck << 3);
            sv[it][0] = *reinterpret_cast<const f32x4*>(src);
            sv[it][1] = *reinterpret_cast<const f32x4*>(src + 4);
        }
#pragma unroll
        for (int it = 0; it < 8; ++it) {
            int row = srow0 + (it << 4);
            int boff = (row << 9) + (((sck << 4)) ^ ((row & 7) << 4));
            *reinterpret_cast<half8*>(PsB + boff) = cvt8(sv[it][0], sv[it][1]);
        }
    }
    __syncthreads();

    for (; c < ntiles; ) {
        const int p0 = c << 7;
        const int cn = c + gridDim.x;
        const bool have_next = (cn < ntiles);

        // ---- issue next chunk's loads (in flight under compute) ----
        if (have_next) {
            const int np0 = cn << 7;
#pragma unroll
            for (int it = 0; it < 8; ++it) {
                int row = srow0 + (it << 4);
                int pr = min(np0 + row, N - 1);
                const float* src = P + (size_t)pr * CC + (sck << 3);
                sv[it][0] = *reinterpret_cast<const f32x4*>(src);
                sv[it][1] = *reinterpret_cast<const f32x4*>(src + 4);
            }
        }

        // ---- MFMA: rows 0..127 x clusters [16w,16w+16) ----
        const char* Pc = PsB;
        const int swz = (lr & 7) << 4;
        f32x4 acc0={0,0,0,0},acc1=acc0,acc2=acc0,acc3=acc0,acc4=acc0,acc5=acc0,acc6=acc0,acc7=acc0;
#define MFMA_RS(accv, rs)                                                              \
        {                                                                              \
            const char* rowp = Pc + ((rs * 16 + lr) << 9);                             \
            _Pragma("unroll")                                                          \
            for (int kk = 0; kk < 8; ++kk) {                                           \
                half8 a = *reinterpret_cast<const half8*>(rowp + (((kk << 6) + (lg << 4)) ^ swz)); \
                accv = __builtin_amdgcn_mfma_f32_16x16x32_f16(a, bfrag[kk], accv, 0, 0, 0); \
            }                                                                          \
        }
        MFMA_RS(acc0, 0) MFMA_RS(acc1, 1) MFMA_RS(acc2, 2) MFMA_RS(acc3, 3)
        MFMA_RS(acc4, 4) MFMA_RS(acc5, 5) MFMA_RS(acc6, 6) MFMA_RS(acc7, 7)
#undef MFMA_RS

        // ---- per-wave argmax (over this wave's 16 clusters) ----
#define ARGMAX_RS(accv, rs)                                                            \
        {                                                                              \
            _Pragma("unroll")                                                          \
            for (int j = 0; j < 4; ++j) {                                              \
                float bv = accv[j]; int bi = myc0 + lr;                                \
                _Pragma("unroll")                                                      \
                for (int msk = 1; msk < 16; msk <<= 1) {                               \
                    float ov = __shfl_xor(bv, msk, 64);                                \
                    int oi = __shfl_xor(bi, msk, 64);                                  \
                    if (ov > bv || (ov == bv && oi < bi)) { bv = ov; bi = oi; }        \
                }                                                                      \
                if (lr == 0) {                                                         \
                    int r = rs * 16 + (lg << 2) + j;                                   \
                    candv[w][r] = bv; candi[w][r] = bi;                                \
                }                                                                      \
            }                                                                          \
        }
        ARGMAX_RS(acc0, 0) ARGMAX_RS(acc1, 1) ARGMAX_RS(acc2, 2) ARGMAX_RS(acc3, 3)
        ARGMAX_RS(acc4, 4) ARGMAX_RS(acc5, 5) ARGMAX_RS(acc6, 6) ARGMAX_RS(acc7, 7)
#undef ARGMAX_RS
        __syncthreads();

        // ---- logits store + cross-wave combine ----
#define STORE_RS(accv, rs)                                                             \
        {                                                                              \
            _Pragma("unroll")                                                          \
            for (int j = 0; j < 4; ++j) {                                              \
                int r = rs * 16 + (lg << 2) + j;                                       \
                int p = p0 + r;                                                        \
                if (p < N) out[((size_t)p << 7) + myc0 + lr] = accv[j];                \
            }                                                                          \
        }
        STORE_RS(acc0, 0) STORE_RS(acc1, 1) STORE_RS(acc2, 2) STORE_RS(acc3, 3)
        STORE_RS(acc4, 4) STORE_RS(acc5, 5) STORE_RS(acc6, 6) STORE_RS(acc7, 7)
#undef STORE_RS
        if (tid < 128) {
            float bv = candv[0][tid]; int bi = candi[0][tid];
#pragma unroll
            for (int wv = 1; wv < 8; ++wv) {
                float ov = candv[wv][tid];
                if (ov > bv) { bv = ov; bi = candi[wv][tid]; } // ascending cluster blocks: strict > keeps lowest
            }
            asg[tid] = bi;
        }
        __syncthreads();

        // ---- segsum: ballot-compact this wave's rows, then pipelined walk ----
        {
            const int rmax = min(128, N - p0);
            const int ra = asg[l], rb = asg[l + 64];
            const bool ma = ((unsigned)(ra - myc0) < 16u) && (l < rmax);
            const bool mb = ((unsigned)(rb - myc0) < 16u) && (l + 64 < rmax);
            const unsigned long long mka = __ballot(ma);
            const unsigned long long mkb = __ballot(mb);
            const int cnta = __popcll(mka);
            if (ma) wq[w][__popcll(mka & below)] = (l << 8) | (ra - myc0);
            if (mb) wq[w][cnta + __popcll(mkb & below)] = ((l + 64) << 8) | (rb - myc0);
            const int qn = cnta + __popcll(mkb);

#define ACC_ONE(E)                                                                     \
            {                                                                          \
                const int r_ = (E) >> 8;                                               \
                const int ar_ = __builtin_amdgcn_readfirstlane((E) & 255);             \
                const int cb_ = (l << 3) ^ ((r_ & 7) << 4);                            \
                half4 hv_ = *reinterpret_cast<const half4*>(Pc + (r_ << 9) + cb_);     \
                f32x4 fv_;                                                             \
                fv_.x = (float)hv_[0]; fv_.y = (float)hv_[1];                          \
                fv_.z = (float)hv_[2]; fv_.w = (float)hv_[3];                          \
                if (ar_ < 8) {                                                         \
                    if (ar_ < 4) { if (ar_ < 2) { if (ar_ == 0) b0 += fv_; else b1 += fv_; } \
                                   else         { if (ar_ == 2) b2 += fv_; else b3 += fv_; } } \
                    else         { if (ar_ < 6) { if (ar_ == 4) b4 += fv_; else b5 += fv_; } \
                                   else         { if (ar_ == 6) b6 += fv_; else b7 += fv_; } } \
                } else {                                                               \
                    if (ar_ < 12){ if (ar_ < 10){ if (ar_ == 8) b8 += fv_; else b9 += fv_; } \
                                   else         { if (ar_ == 10) b10 += fv_; else b11 += fv_; } } \
                    else         { if (ar_ < 14){ if (ar_ == 12) b12 += fv_; else b13 += fv_; } \
                                   else         { if (ar_ == 14) b14 += fv_; else b15 += fv_; } } \
                }                                                                      \
            }
            int i = 0;
            for (; i + 4 <= qn; i += 4) {
                const int e0 = wq[w][i], e1 = wq[w][i + 1], e2 = wq[w][i + 2], e3 = wq[w][i + 3];
                ACC_ONE(e0) ACC_ONE(e1) ACC_ONE(e2) ACC_ONE(e3)
            }
            for (; i < qn; ++i) {
                const int e = wq[w][i];
                ACC_ONE(e)
            }
#undef ACC_ONE
        }
        __syncthreads();   // all reads of Ps done

        // ---- write prefetched regs into Ps ----
        if (have_next) {
#pragma unroll
            for (int it = 0; it < 8; ++it) {
                int row = srow0 + (it << 4);
                int boff = (row << 9) + (((sck << 4)) ^ ((row & 7) << 4));
                *reinterpret_cast<half8*>(PsB + boff) = cvt8(sv[it][0], sv[it][1]);
            }
            __syncthreads();
        }
        c = cn;
    }

    // ---- flush bins to partial[bid] ----
    {
        float* pb = partial + (size_t)blockIdx.x * (QQ * CC) + (size_t)myc0 * CC + (l << 2);
        f32x4 bb[16] = {b0,b1,b2,b3,b4,b5,b6,b7,b8,b9,b10,b11,b12,b13,b14,b15};
#pragma unroll
        for (int i = 0; i < 16; ++i)
            *reinterpret_cast<f32x4*>(pb + (size_t)i * CC) = bb[i];
    }
}

// ---------------- K4: reduce partials + bottleneck LN -> Wb -> LN, + residual --
__global__ __launch_bounds__(256) void k_bottleneck(
    const float* __restrict__ partial, int nparts,
    const float* __restrict__ lnb1w, const float* __restrict__ lnb1b,
    const float* __restrict__ Wb,
    const float* __restrict__ lnb2w, const float* __restrict__ lnb2b,
    const float* __restrict__ cc, float* __restrict__ out2)
{
    const int q = blockIdx.x, t = threadIdx.x;
    __shared__ float xs[CC];
    __shared__ float red[4];

    float v = 0.f;
    {
        const float* src = partial + (size_t)q * CC + t;
        int part = 0;
        for (; part + 7 < nparts; part += 8) {
            float s0 = src[(size_t)(part + 0) * (QQ * CC)];
            float s1 = src[(size_t)(part + 1) * (QQ * CC)];
            float s2 = src[(size_t)(part + 2) * (QQ * CC)];
            float s3 = src[(size_t)(part + 3) * (QQ * CC)];
            float s4 = src[(size_t)(part + 4) * (QQ * CC)];
            float s5 = src[(size_t)(part + 5) * (QQ * CC)];
            float s6 = src[(size_t)(part + 6) * (QQ * CC)];
            float s7 = src[(size_t)(part + 7) * (QQ * CC)];
            v += ((s0 + s1) + (s2 + s3)) + ((s4 + s5) + (s6 + s7));
        }
        for (; part < nparts; ++part)
            v += src[(size_t)part * (QQ * CC)];
    }

    float s = block_sum256(v, red, t);
    float m = s * (1.0f / CC);
    float d = v - m;
    float s2 = block_sum256(d * d, red, t);
    float rstd = rsqrtf(s2 * (1.0f / CC) + 1e-5f);
    xs[t] = d * rstd * lnb1w[t] + lnb1b[t];
    __syncthreads();

    float acc = 0.f;
    {
        const float* wp = Wb + t * CC;
#pragma unroll 8
        for (int k = 0; k < CC; k += 4) {
            f32x4 wv = *(const f32x4*)(wp + k);
            acc += xs[k] * wv.x + xs[k + 1] * wv.y + xs[k + 2] * wv.z + xs[k + 3] * wv.w;
        }
    }
    float zs = block_sum256(acc, red, t);
    float zm = zs * (1.0f / CC);
    float zd = acc - zm;
    float zs2 = block_sum256(zd * zd, red, t);
    float zr = rsqrtf(zs2 * (1.0f / CC) + 1e-5f);
    out2[q * CC + t] = cc[q * CC + t] + zd * zr * lnb2w[t] + lnb2b[t];
}

extern "C" void kernel_launch(void* const* d_in, const int* in_sizes, int n_in,
                              void* d_out, int out_size, void* d_ws, size_t ws_size,
                              hipStream_t stream) {
    const float* cc   = (const float*)d_in[0];
    const float* P    = (const float*)d_in[1];
    const float* ln0w = (const float*)d_in[2];
    const float* ln0b = (const float*)d_in[3];
    const float* W1   = (const float*)d_in[4];
    const float* b1   = (const float*)d_in[5];
    const float* W2   = (const float*)d_in[6];
    const float* b2   = (const float*)d_in[7];
    const float* W3   = (const float*)d_in[8];
    const float* b3   = (const float*)d_in[9];
    const float* lnb1w = (const float*)d_in[10];
    const float* lnb1b = (const float*)d_in[11];
    const float* Wb   = (const float*)d_in[12];
    const float* lnb2w = (const float*)d_in[13];
    const float* lnb2b = (const float*)d_in[14];

    const int N = in_sizes[1] / CC;

    char* ws = (char*)d_ws;
    unsigned short* Mh = (unsigned short*)ws;               // 65536 B
    float* partial = (float*)(ws + 65536);                  // 256 * 128 KB = 32 MB

    float* logits = (float*)d_out;                          // [N][128]
    float* out2 = (float*)d_out + (size_t)N * QQ;           // [128][256]

    k_mlp_head<<<QQ, 256, 0, stream>>>(cc, ln0w, ln0b, W1, b1, W2, b2, W3, b3, Mh);

    const int ntiles = (N + 127) >> 7;
    const int nblk = 256;
    k_fused<<<nblk, 512, 0, stream>>>(P, Mh, logits, partial, N, ntiles);

    k_bottleneck<<<QQ, 256, 0, stream>>>(partial, nblk, lnb1w, lnb1b, Wb, lnb2w, lnb2b, cc, out2);
}